// Round 13
// baseline (207.863 us; speedup 1.0000x reference)
//
#include <hip/hip_runtime.h>

typedef __attribute__((ext_vector_type(8))) short bf16x8;
typedef __attribute__((ext_vector_type(4))) float f32x4;
typedef __attribute__((ext_vector_type(2))) unsigned int u32x2;
typedef __attribute__((ext_vector_type(4))) unsigned int u32x4;
typedef __attribute__((ext_vector_type(2))) __bf16 bf16x2t;
typedef unsigned short u16;
typedef unsigned int u32;
typedef unsigned long long u64;

#define DI __device__ __forceinline__

// Problem constants: B=8, A=1024, NB=64, NAB=NF=128, NG=25, NI=3
#define NKNOT 2048

DI float b2f(u16 u){ union{u32 i; float f;} v; v.i = ((u32)u)<<16; return v.f; }
DI float asf(u32 u){ union{u32 i; float f;} v; v.i = u; return v.f; }
DI u16 f2b(float f){ union{float f; u32 i;} v; v.f=f; u32 u=v.i;
                     return (u16)((u + 0x7fffu + ((u>>16)&1u))>>16); }
DI u32 pk2(float lo, float hi){
#if __has_builtin(__builtin_amdgcn_cvt_pk_bf16_f32)
  bf16x2t h = __builtin_amdgcn_cvt_pk_bf16_f32(lo, hi);
  u32 d; __builtin_memcpy(&d, &h, 4); return d;
#else
  return (u32)f2b(lo) | ((u32)f2b(hi)<<16);
#endif
}
DI float fexp2(float x){
#if __has_builtin(__builtin_amdgcn_exp2f)
  return __builtin_amdgcn_exp2f(x);
#else
  return __expf(x*0.6931471805599453f);
#endif
}
DI float flog2(float x){
#if __has_builtin(__builtin_amdgcn_logf)
  return __builtin_amdgcn_logf(x);
#else
  return __logf(x)*1.4426950408889634f;
#endif
}
DI float ldin(const void* p, size_t i, int isbf){
  return isbf ? b2f(((const u16*)p)[i]) : ((const float*)p)[i];
}
DI f32x4 ldin4(const void* p, size_t i, int isbf){
  if(isbf){
    u32x2 d = *(const u32x2*)((const u16*)p + i);
    f32x4 r;
    r[0] = b2f((u16)(d[0]&0xffff)); r[1] = b2f((u16)(d[0]>>16));
    r[2] = b2f((u16)(d[1]&0xffff)); r[3] = b2f((u16)(d[1]>>16));
    return r;
  }
  return *(const f32x4*)((const float*)p + i);
}
DI int probe_bf(const void* nmask){ return ((const u16*)nmask)[0] == 0x3F80u; }

DI f32x4 mfma16(bf16x8 a, bf16x8 b, f32x4 c){
  return __builtin_amdgcn_mfma_f32_16x16x32_bf16(a,b,c,0,0,0);
}
DI bf16x8 ldfragA_f32(const float* p){
  f32x4 a = ((const f32x4*)p)[0], b = ((const f32x4*)p)[1];
  union{ u32 d[4]; bf16x8 v; } u;
  u.d[0]=pk2(a[0],a[1]); u.d[1]=pk2(a[2],a[3]);
  u.d[2]=pk2(b[0],b[1]); u.d[3]=pk2(b[2],b[3]);
  return u.v;
}
DI float sspf(float x){ return __logf(1.f + __expf(x)) - 0.6931471805599453f; }

// WF layout per interaction (u16 offsets; frag = 512 u16):
//   in2f frags off 24576 | f2o off 40960 | dense off 57344
// (fw1/fw2 regions unused: table blocks self-build from raw weights)
#define WF_STRIDE 73728
#define WF_IN2F   24576
#define WF_F2O    40960
#define WF_DEN    57344

// Block ranges in the merged setup kernel (slow blocks FIRST so they start
// at t=0 and overlap the wide embed/desc phases instead of forming a tail):
//   [0,96)       table: TT from raw fw1/fb1/fw2/fb2 (hoisted-load self-build)
//   [96,224)     proj:  Y = emb[z] @ in2f[0] (hoisted-load self-build)
//   [224,1248)   embed: X = emb[z]
//   [1248,3296)  dist -> desc (ballot-compacted) + CNT
//   [3296,3368)  wfrag: in2f/f2o/dense B-frags for k_iter
__global__ __launch_bounds__(256) void k_setup(const void* __restrict__ pos,
                                               const void* __restrict__ cell,
                                               const void* __restrict__ cello,
                                               const void* __restrict__ nmask,
                                               const void* __restrict__ emb,
                                               const void* __restrict__ fw1,
                                               const void* __restrict__ fb1,
                                               const void* __restrict__ fw2,
                                               const void* __restrict__ fb2,
                                               const void* __restrict__ in2f,
                                               const void* __restrict__ f2o,
                                               const void* __restrict__ den,
                                               const int* __restrict__ z,
                                               const int* __restrict__ nbrs,
                                               float* __restrict__ X,
                                               u32x2* __restrict__ DESC,
                                               u32* __restrict__ CNT,
                                               u16* __restrict__ WF,
                                               u32x2* __restrict__ TT,
                                               float* __restrict__ Y){
  __shared__ __align__(16) u16 Hb[4][16][168];
  int isbf = probe_bf(nmask);
  int bx = blockIdx.x, tid = threadIdx.x;
  int widx = tid>>6;
  int lane = tid & 63;
  int q = lane>>4, l15 = lane&15;

  if(bx < 96){
    // ---- table: self-build fw1/fw2 frags with HOISTED loads ----
    int wid = bx*4 + widx;           // 0..383
    int i  = wid>>7;
    int kb = (wid&127)*16;
    u16 (*H)[168] = Hb[widx];

    const float width = 5.0f/24.0f;
    const float c2 = (-0.5f/(width*width))*1.4426950408889634f;
    const float l2e = 1.4426950408889634f;
    float r = (float)(kb + l15) * (5.0f/(float)(NKNOT-1));

    float gv[8];
    #pragma unroll
    for(int j=0;j<8;j++){
      int k = q*8+j;
      if(k < 25){ float t = fmaf(-width,(float)k,r); gv[j] = fexp2(c2*t*t); }
      else gv[j] = (k==25) ? 1.f : 0.f;
    }
    union{ u32 d[4]; bf16x8 v; } afu;
    afu.d[0]=pk2(gv[0],gv[1]); afu.d[1]=pk2(gv[2],gv[3]);
    afu.d[2]=pk2(gv[4],gv[5]); afu.d[3]=pk2(gv[6],gv[7]);
    bf16x8 af = afu.v;

    f32x4 acc[8];
    // fw1 pass: rows k=q*8+j (<25 -> fw1*log2e, ==25 -> fb1*log2e, else 0)
    #pragma unroll
    for(int th=0; th<2; ++th){
      float v[4][8];
      #pragma unroll
      for(int tt=0;tt<4;tt++){
        int c = (th*4+tt)*16 + l15;
        #pragma unroll
        for(int j=0;j<8;j++){
          int k = q*8+j;
          float x;
          if(k < 25)      x = ldin(fw1, (size_t)i*3200 + (size_t)k*128 + c, isbf);
          else if(k==25)  x = ldin(fb1, (size_t)i*128 + c, isbf);
          else            x = 0.f;
          v[tt][j] = x * l2e;
        }
      }
      #pragma unroll
      for(int tt=0;tt<4;tt++){
        union{ u32 d[4]; bf16x8 w; } wu;
        wu.d[0]=pk2(v[tt][0],v[tt][1]); wu.d[1]=pk2(v[tt][2],v[tt][3]);
        wu.d[2]=pk2(v[tt][4],v[tt][5]); wu.d[3]=pk2(v[tt][6],v[tt][7]);
        acc[th*4+tt] = mfma16(wu.w, af, (f32x4){0.f,0.f,0.f,0.f});
      }
    }
    const float ln2 = 0.69314718055994531f;
    #pragma unroll
    for(int t=0;t<8;t++){
      float h0 = fmaf(flog2(1.f+fexp2(acc[t][0])), ln2, -ln2);
      float h1 = fmaf(flog2(1.f+fexp2(acc[t][1])), ln2, -ln2);
      float h2 = fmaf(flog2(1.f+fexp2(acc[t][2])), ln2, -ln2);
      float h3 = fmaf(flog2(1.f+fexp2(acc[t][3])), ln2, -ln2);
      u32x2 d; d[0]=pk2(h0,h1); d[1]=pk2(h2,h3);
      *(u32x2*)(&H[l15][t*16 + q*4]) = d;
    }
    { // bias block cols 128..159: col128 = 1.0 (adds fb2), rest 0
      u32x2 zb; zb[0] = (q==0) ? pk2(1.f, 0.f) : 0u; zb[1] = 0u;
      *(u32x2*)(&H[l15][128 + q*4]) = zb;
      u32x2 zz; zz[0]=0u; zz[1]=0u;
      *(u32x2*)(&H[l15][144 + q*4]) = zz;
    }
    #pragma unroll
    for(int t=0;t<8;t++) acc[t] = (f32x4){0.f,0.f,0.f,0.f};
    // fw2 pass: rows k=kk*32+q*8+j (<128 -> fw2, ==128 -> fb2, else 0)
    #pragma unroll
    for(int kk=0;kk<5;kk++){
      bf16x8 a2 = *(const bf16x8*)(&H[l15][kk*32 + q*8]);
      #pragma unroll
      for(int th=0; th<2; ++th){
        float v[4][8];
        #pragma unroll
        for(int tt=0;tt<4;tt++){
          int c = (th*4+tt)*16 + l15;
          #pragma unroll
          for(int j=0;j<8;j++){
            int k = kk*32 + q*8 + j;
            float x;
            if(k < 128)      x = ldin(fw2, (size_t)i*16384 + (size_t)k*128 + c, isbf);
            else if(k==128)  x = ldin(fb2, (size_t)i*128 + c, isbf);
            else             x = 0.f;
            v[tt][j] = x;
          }
        }
        #pragma unroll
        for(int tt=0;tt<4;tt++){
          union{ u32 d[4]; bf16x8 w; } wu;
          wu.d[0]=pk2(v[tt][0],v[tt][1]); wu.d[1]=pk2(v[tt][2],v[tt][3]);
          wu.d[2]=pk2(v[tt][4],v[tt][5]); wu.d[3]=pk2(v[tt][6],v[tt][7]);
          acc[th*4+tt] = mfma16(a2, wu.w, acc[th*4+tt]);
        }
      }
    }
    // store interleaved: row -> TT[row].slot0, TT[row-1].slot1
    {
      u32x2* ttb = TT + (size_t)i*NKNOT*64;
      int row = kb + l15;
      #pragma unroll
      for(int t=0;t<8;t++){
        u32 d0 = pk2(acc[t][0],acc[t][1]);
        u32 d1 = pk2(acc[t][2],acc[t][3]);
        int l = t*8 + q*2;
        ((u32*)&ttb[(size_t)row*64 + l    ])[0] = d0;
        ((u32*)&ttb[(size_t)row*64 + l + 1])[0] = d1;
        if(row > 0){
          ((u32*)&ttb[(size_t)(row-1)*64 + l    ])[1] = d0;
          ((u32*)&ttb[(size_t)(row-1)*64 + l + 1])[1] = d1;
        }
      }
    }
    return;
  }
  if(bx < 224){
    // ---- proj: y0 = emb[z] @ in2f[0], hoisted-load self-build ----
    int wid2 = (bx-96)*4 + widx;     // 0..511
    int row0 = wid2*16;
    int zr = z[row0 + l15];
    f32x4 acc[8];
    #pragma unroll
    for(int t=0;t<8;t++) acc[t] = (f32x4){0.f,0.f,0.f,0.f};
    #pragma unroll
    for(int kk=0;kk<4;kk++){
      bf16x8 xf;
      if(isbf) xf = *(const bf16x8*)((const u16*)emb + (size_t)zr*128 + kk*32 + q*8);
      else     xf = ldfragA_f32((const float*)emb + (size_t)zr*128 + kk*32 + q*8);
      #pragma unroll
      for(int th=0; th<2; ++th){
        float v[4][8];
        #pragma unroll
        for(int tt=0;tt<4;tt++){
          int c = (th*4+tt)*16 + l15;
          #pragma unroll
          for(int j=0;j<8;j++)
            v[tt][j] = ldin(in2f, (size_t)(kk*32+q*8+j)*128 + c, isbf);
        }
        #pragma unroll
        for(int tt=0;tt<4;tt++){
          union{ u32 d[4]; bf16x8 w; } wu;
          wu.d[0]=pk2(v[tt][0],v[tt][1]); wu.d[1]=pk2(v[tt][2],v[tt][3]);
          wu.d[2]=pk2(v[tt][4],v[tt][5]); wu.d[3]=pk2(v[tt][6],v[tt][7]);
          acc[th*4+tt] = mfma16(wu.w, xf, acc[th*4+tt]);
        }
      }
    }
    #pragma unroll
    for(int t=0;t<8;t++)
      *(f32x4*)(Y + (size_t)(row0+l15)*128 + t*16 + q*4) = acc[t];
    return;
  }
  if(bx < 1248){
    int idx = (bx-224)*256 + tid;              // < 8192*32
    int a = idx>>5, f4 = (idx&31)*4;
    f32x4 e = ldin4(emb, (size_t)z[a]*128 + f4, isbf);
    *(f32x4*)(X + (size_t)a*128 + f4) = e;
    return;
  }
  if(bx < 3296){
    int pairIdx = (bx-1248)*256 + tid;         // < 8192*64
    int atom = pairIdx>>6;
    int b = atom>>10;
    int nb = nbrs[pairIdx];
    int jrow = (b<<10) + nb;
    float pi0=ldin(pos,atom*3+0,isbf), pi1=ldin(pos,atom*3+1,isbf), pi2=ldin(pos,atom*3+2,isbf);
    float pj0=ldin(pos,jrow*3+0,isbf), pj1=ldin(pos,jrow*3+1,isbf), pj2=ldin(pos,jrow*3+2,isbf);
    float co0=ldin(cello,(size_t)pairIdx*3+0,isbf),
          co1=ldin(cello,(size_t)pairIdx*3+1,isbf),
          co2=ldin(cello,(size_t)pairIdx*3+2,isbf);
    size_t cb = (size_t)b*9;
    pj0 += co0*ldin(cell,cb+0,isbf) + co1*ldin(cell,cb+3,isbf) + co2*ldin(cell,cb+6,isbf);
    pj1 += co0*ldin(cell,cb+1,isbf) + co1*ldin(cell,cb+4,isbf) + co2*ldin(cell,cb+7,isbf);
    pj2 += co0*ldin(cell,cb+2,isbf) + co1*ldin(cell,cb+5,isbf) + co2*ldin(cell,cb+8,isbf);
    float d0 = pj0-pi0, d1 = pj1-pi1, d2 = pj2-pi2;
    float dd = d0*d0 + d1*d1 + d2*d2;
    float m  = ldin(nmask,pairIdx,isbf);
    float r  = sqrtf(m>0.f ? dd : 1.f) * m;
    float c  = 0.5f*(__cosf(r*3.14159265358979f/5.f)+1.f) * ((r<5.f)?1.f:0.f) * m;
    float s  = r * ((float)(NKNOT-1)/5.0f);
    int   k  = (int)s; if(k > NKNOT-2) k = NKNOT-2;
    float fr = s - (float)k;
    float a0 = c*(1.f-fr), a1 = c*fr;
    union{ _Float16 h[2]; u32 u; } pa;
    pa.h[0] = (_Float16)a0; pa.h[1] = (_Float16)a1;
    // ballot-compact: active pairs -> [0,cnt), zero-descs -> [cnt,64)
    int lane2 = tid & 63;
    int act = (c > 0.f);
    u64 bal = __ballot(act);
    u64 below = bal & ((1ULL<<lane2)-1ULL);
    int cnt = (int)__popcll(bal);
    int apre = (int)__popcll(below);
    int pos_ = act ? apre : (cnt + (lane2 - apre));
    u32x2 dsc;
    if(act){ dsc[0] = pa.u; dsc[1] = (u32)k | ((u32)nb<<16); }
    else   { dsc[0] = 0u;   dsc[1] = 0u; }
    DESC[(size_t)atom*64 + pos_] = dsc;
    if(lane2 == 0) CNT[atom] = (u32)cnt;
    return;
  }
  // ---- wfrag: wid in [0,288) = 3 interactions x {in2f,f2o,den} x 32 frags
  {
    int wid = (bx-3296)*4 + widx;
    int i = wid/96, r = wid%96;
    int mat = r>>5, kk = (r>>3)&3, t = r&7;
    const void* src; int off;
    switch(mat){
      case 0:  src = in2f; off=WF_IN2F; break;
      case 1:  src = f2o;  off=WF_F2O;  break;
      default: src = den;  off=WF_DEN;  break;
    }
    size_t sbase = (size_t)i*16384;
    int c = t*16 + l15;
    bf16x8 frag;
    #pragma unroll
    for(int j=0;j<8;j++){
      int k = kk*32 + q*8 + j;
      frag[j] = (short)f2b(ldin(src, sbase + (size_t)k*128 + c, isbf));
    }
    *(bf16x8*)(WF + (size_t)i*WF_STRIDE + off + ((kk*8+t)*64 + lane)*8) = frag;
  }
}

// ---------------------------------------------------------------------------
// Fused iteration: half-wave gather over compacted active pairs with
// PING-PONG SOFTWARE PIPELINING — group g+1's 4 VMEM loads are issued
// BEFORE group g's compute, so loads stay in flight across the compute
// instead of a full vmcnt drain every group.  Otherwise identical to R8/R12
// (same summation order -> bit-identical output).
// 512 thr = 8 waves = 8 atoms/block; grid 1024 = 4 blocks/CU, co-resident.
#define LOADG(g, cu, tt, yv) { \
  _Pragma("unroll") \
  for(int s=0;s<2;++s){ \
    int p0 = (g)*4 + s*2; \
    u32 d1a = __builtin_amdgcn_readlane(dsc[1], p0); \
    u32 d1b = __builtin_amdgcn_readlane(dsc[1], p0+1); \
    u32 d0a = __builtin_amdgcn_readlane(dsc[0], p0); \
    u32 d0b = __builtin_amdgcn_readlane(dsc[0], p0+1); \
    u32 d1 = h ? d1b : d1a; \
    cu[s]  = h ? d0b : d0a; \
    u32 krow = d1 & 0xffffu; \
    u32 nbr  = d1 >> 16; \
    tt[s] = *(const u32x4*)(Tc + ((size_t)krow<<9) + boff); \
    yv[s] = *(const f32x4*)(Yb + ((size_t)nbr<<9) + boff); \
  } }

#define COMPUTEG(cu, tt, yv) { \
  _Pragma("unroll") \
  for(int s=0;s<2;++s){ \
    union{ u32 u; _Float16 hh[2]; } pa; pa.u = cu[s]; \
    float a0 = (float)pa.hh[0], a1 = (float)pa.hh[1]; \
    float w0 = fmaf(a1, asf(tt[s][1]<<16),          a0*asf(tt[s][0]<<16)); \
    float w1 = fmaf(a1, asf(tt[s][1]&0xffff0000u),  a0*asf(tt[s][0]&0xffff0000u)); \
    float w2 = fmaf(a1, asf(tt[s][3]<<16),          a0*asf(tt[s][2]<<16)); \
    float w3 = fmaf(a1, asf(tt[s][3]&0xffff0000u),  a0*asf(tt[s][2]&0xffff0000u)); \
    acc4[0] = fmaf(w0, yv[s][0], acc4[0]); \
    acc4[1] = fmaf(w1, yv[s][1], acc4[1]); \
    acc4[2] = fmaf(w2, yv[s][2], acc4[2]); \
    acc4[3] = fmaf(w3, yv[s][3], acc4[3]); \
  } }

__global__ __launch_bounds__(512, 8) void k_iter(const u32x2* __restrict__ desc,
                                                 const u32* __restrict__ CNT,
                                                 const u32x2* __restrict__ TT,
                                                 const float* __restrict__ Yr,
                                                 float* __restrict__ X,
                                                 float* __restrict__ Yw,
                                                 const u16* __restrict__ f2of,
                                                 const u16* __restrict__ denf,
                                                 const u16* __restrict__ in2fN,
                                                 const void* __restrict__ f2ob,
                                                 const void* __restrict__ denb,
                                                 const void* __restrict__ nmask,
                                                 void* __restrict__ OUT,
                                                 int last, int iidx){
  __shared__ __align__(16) float AGGs[16][132];
  __shared__ __align__(16) u16 Tb[16][136];
  __shared__ __align__(16) u16 Xw[16][136];
  int isbf = probe_bf(nmask);
  int widx = threadIdx.x>>6;        // 0..7
  int lane = threadIdx.x & 63;
  int q = lane>>4, l15 = lane&15;
  int bid = blockIdx.x;
  int row0 = (bid & 7)*1024 + (bid >> 3)*8;   // 8 atoms/block, batch = bid%8

  // ---- Phase 1: CFConv over active pairs, half-wave per pair, pipelined.
  {
    int atom = row0 + widx;
    int cnt = (int)__builtin_amdgcn_readfirstlane(CNT[atom]);
    int ng  = (cnt + 3) >> 2;                    // chunks of 4 pairs
    u32x2 dsc = desc[(size_t)atom*64 + lane];    // lane p holds desc of slot p
    const char* Yb = (const char*)(Yr + (size_t)(atom & ~1023)*128);
    const char* Tc = (const char*)TT;
    int h   = lane>>5;                            // half index: pair parity
    int j32 = lane&31;                            // filters 4*j32 .. 4*j32+3
    int boff = j32<<4;                            // 16 B per lane
    f32x4 acc4 = (f32x4){0.f,0.f,0.f,0.f};
    u32 cuA[2]; u32x4 ttA[2]; f32x4 yvA[2];
    u32 cuB[2]; u32x4 ttB[2]; f32x4 yvB[2];
    if(ng > 0){
      LOADG(0, cuA, ttA, yvA);
      int g = 0;
      #pragma unroll 1
      while(true){
        if(g+1 < ng) LOADG(g+1, cuB, ttB, yvB);
        COMPUTEG(cuA, ttA, yvA);
        ++g; if(g >= ng) break;
        if(g+1 < ng) LOADG(g+1, cuA, ttA, yvA);
        COMPUTEG(cuB, ttB, yvB);
        ++g; if(g >= ng) break;
      }
    }
    *(f32x4*)(&AGGs[widx + 8*h][j32*4]) = acc4;   // partials: rows a / a+8
  }
  __syncthreads();

  // ---- Phase 2: v = ssp(agg @ f2out + b); t = widx; merge halves via shfl.
  {
    int t = widx;
    f32x4 acc = (f32x4){0.f,0.f,0.f,0.f};
    #pragma unroll
    for(int kk=0;kk<4;kk++){
      bf16x8 gf = ldfragA_f32(&AGGs[l15][kk*32 + q*8]);
      bf16x8 wv = *(const bf16x8*)(f2of + ((kk*8+t)*64 + lane)*8);
      acc = mfma16(wv, gf, acc);
    }
    #pragma unroll
    for(int r=0;r<4;r++) acc[r] += __shfl_xor(acc[r], 8);
    f32x4 bv = ldin4(f2ob, (size_t)iidx*128 + t*16 + q*4, isbf);
    u32x2 d;
    d[0] = pk2(sspf(acc[0]+bv[0]), sspf(acc[1]+bv[1]));
    d[1] = pk2(sspf(acc[2]+bv[2]), sspf(acc[3]+bv[3]));
    *(u32x2*)(&Tb[l15][t*16 + q*4]) = d;   // rows 8-15 duplicate rows 0-7
  }
  __syncthreads();

  // ---- Phase 2b: dense @ + bias + X residual; stores guarded to l15<8.
  {
    int t = widx;
    f32x4 acc = (f32x4){0.f,0.f,0.f,0.f};
    #pragma unroll
    for(int kk=0;kk<4;kk++){
      bf16x8 tf = *(const bf16x8*)(&Tb[l15][kk*32 + q*8]);
      bf16x8 wv = *(const bf16x8*)(denf + ((kk*8+t)*64 + lane)*8);
      acc = mfma16(wv, tf, acc);
    }
    size_t idx = (size_t)(row0+l15)*128 + t*16 + q*4;
    f32x4 bv = ldin4(denb, (size_t)iidx*128 + t*16 + q*4, isbf);
    f32x4 xv = *(const f32x4*)(X + idx);
    f32x4 xn;
    #pragma unroll
    for(int r=0;r<4;r++) xn[r] = xv[r] + acc[r] + bv[r];
    if(l15 < 8){
      *(f32x4*)(X + idx) = xn;
      if(last){
        if(isbf){
          u32x2 o; o[0]=pk2(xn[0],xn[1]); o[1]=pk2(xn[2],xn[3]);
          *(u32x2*)((u16*)OUT + idx) = o;
        } else {
          *(f32x4*)((float*)OUT + idx) = xn;
        }
      }
    }
    if(!last){
      u32x2 d; d[0]=pk2(xn[0],xn[1]); d[1]=pk2(xn[2],xn[3]);
      *(u32x2*)(&Xw[l15][t*16 + q*4]) = d;
    }
  }
  if(!last){
    __syncthreads();
    // ---- Phase 3: y_next = x_new @ in2f_next (other Y buffer); l15<8 stores.
    {
      int t = widx;
      f32x4 acc = (f32x4){0.f,0.f,0.f,0.f};
      #pragma unroll
      for(int kk=0;kk<4;kk++){
        bf16x8 xf = *(const bf16x8*)(&Xw[l15][kk*32 + q*8]);
        bf16x8 wv = *(const bf16x8*)(in2fN + ((kk*8+t)*64 + lane)*8);
        acc = mfma16(wv, xf, acc);
      }
      if(l15 < 8)
        *(f32x4*)(Yw + (size_t)(row0+l15)*128 + t*16 + q*4) = acc;
    }
  }
}

// ---------------------------------------------------------------------------
extern "C" void kernel_launch(void* const* d_in, const int* in_sizes, int n_in,
                              void* d_out, int out_size, void* d_ws, size_t ws_size,
                              hipStream_t stream){
  const void* pos   = d_in[0];
  const void* cell  = d_in[1];
  const void* cello = d_in[2];
  const void* nmask = d_in[3];
  // d_in[4] atom_mask: unused by the output
  const void* emb   = d_in[5];
  const void* fw1   = d_in[6];
  const void* fb1   = d_in[7];
  const void* fw2   = d_in[8];
  const void* fb2   = d_in[9];
  const void* in2f  = d_in[10];
  const void* f2o   = d_in[11];
  const void* f2ob  = d_in[12];
  const void* den   = d_in[13];
  const void* denb  = d_in[14];
  const int* z      = (const int*)d_in[15];
  const int* nbrs   = (const int*)d_in[16];

  char* ws = (char*)d_ws;
  float* X    = (float*)(ws);                 //  4 MB fp32 features
  float* Y    = (float*)(ws +  4194304);      //  4 MB projected features (ping)
  float* Y2   = (float*)(ws +  8388608);      //  4 MB projected features (pong)
  u32x2* DESC = (u32x2*)(ws + 12582912);      //  4 MB pair descriptors
  u16*   WF   = (u16*)  (ws + 16777216);      // 432 KB weight B-frags
  u32x2* TT   = (u32x2*)(ws + 17301504);      //  3 MB interleaved knot-pair table
  u32*   CNT  = (u32*)  (ws + 20447232);      // 32 KB per-atom active counts

  k_setup<<<3368, 256, 0, stream>>>(pos, cell, cello, nmask, emb,
                                    fw1, fb1, fw2, fb2, in2f, f2o, den,
                                    z, nbrs, X, DESC, CNT, WF, TT, Y);

  for(int i=0;i<3;i++){
    const u16* base = WF + (size_t)i*WF_STRIDE;
    const u16* in2fN = (i<2) ? (WF + (size_t)(i+1)*WF_STRIDE + WF_IN2F) : WF;
    const float* Yrd = (i&1) ? Y2 : Y;
    float*       Ywr = (i&1) ? Y  : Y2;
    k_iter<<<1024, 512, 0, stream>>>(DESC, CNT, TT + (size_t)i*NKNOT*64, Yrd, X, Ywr,
                                     base + WF_F2O, base + WF_DEN, in2fN,
                                     f2ob, denb, nmask,
                                     d_out, (i==2) ? 1 : 0, i);
  }
}

// Round 16
// 167.092 us; speedup vs baseline: 1.2440x; 1.2440x over previous
//
#include <hip/hip_runtime.h>

typedef __attribute__((ext_vector_type(8))) short bf16x8;
typedef __attribute__((ext_vector_type(4))) float f32x4;
typedef __attribute__((ext_vector_type(2))) unsigned int u32x2;
typedef __attribute__((ext_vector_type(4))) unsigned int u32x4;
typedef __attribute__((ext_vector_type(2))) __bf16 bf16x2t;
typedef unsigned short u16;
typedef unsigned int u32;
typedef unsigned long long u64;

#define DI __device__ __forceinline__

// Problem constants: B=8, A=1024, NB=64, NAB=NF=128, NG=25, NI=3
#define NKNOT 2048

DI float b2f(u16 u){ union{u32 i; float f;} v; v.i = ((u32)u)<<16; return v.f; }
DI float asf(u32 u){ union{u32 i; float f;} v; v.i = u; return v.f; }
DI u16 f2b(float f){ union{float f; u32 i;} v; v.f=f; u32 u=v.i;
                     return (u16)((u + 0x7fffu + ((u>>16)&1u))>>16); }
DI u32 pk2(float lo, float hi){
#if __has_builtin(__builtin_amdgcn_cvt_pk_bf16_f32)
  bf16x2t h = __builtin_amdgcn_cvt_pk_bf16_f32(lo, hi);
  u32 d; __builtin_memcpy(&d, &h, 4); return d;
#else
  return (u32)f2b(lo) | ((u32)f2b(hi)<<16);
#endif
}
DI float fexp2(float x){
#if __has_builtin(__builtin_amdgcn_exp2f)
  return __builtin_amdgcn_exp2f(x);
#else
  return __expf(x*0.6931471805599453f);
#endif
}
DI float flog2(float x){
#if __has_builtin(__builtin_amdgcn_logf)
  return __builtin_amdgcn_logf(x);
#else
  return __logf(x)*1.4426950408889634f;
#endif
}
DI float ldin(const void* p, size_t i, int isbf){
  return isbf ? b2f(((const u16*)p)[i]) : ((const float*)p)[i];
}
DI f32x4 ldin4(const void* p, size_t i, int isbf){
  if(isbf){
    u32x2 d = *(const u32x2*)((const u16*)p + i);
    f32x4 r;
    r[0] = b2f((u16)(d[0]&0xffff)); r[1] = b2f((u16)(d[0]>>16));
    r[2] = b2f((u16)(d[1]&0xffff)); r[3] = b2f((u16)(d[1]>>16));
    return r;
  }
  return *(const f32x4*)((const float*)p + i);
}
DI int probe_bf(const void* nmask){ return ((const u16*)nmask)[0] == 0x3F80u; }

DI f32x4 mfma16(bf16x8 a, bf16x8 b, f32x4 c){
  return __builtin_amdgcn_mfma_f32_16x16x32_bf16(a,b,c,0,0,0);
}
DI bf16x8 ldfragA_f32(const float* p){
  f32x4 a = ((const f32x4*)p)[0], b = ((const f32x4*)p)[1];
  union{ u32 d[4]; bf16x8 v; } u;
  u.d[0]=pk2(a[0],a[1]); u.d[1]=pk2(a[2],a[3]);
  u.d[2]=pk2(b[0],b[1]); u.d[3]=pk2(b[2],b[3]);
  return u.v;
}
DI float sspf(float x){ return __logf(1.f + __expf(x)) - 0.6931471805599453f; }

// WF layout per interaction (u16 offsets; frag = 512 u16):
//   in2f frags off 24576 | f2o off 40960 | dense off 57344
#define WF_STRIDE 73728
#define WF_IN2F   24576
#define WF_F2O    40960
#define WF_DEN    57344

// Block ranges in the merged setup kernel (slow blocks FIRST):
//   [0,96)       table | [96,224) proj | [224,1248) embed |
//   [1248,3296)  dist->desc (ballot-compacted) + CNT | [3296,3368) wfrag
__global__ __launch_bounds__(256) void k_setup(const void* __restrict__ pos,
                                               const void* __restrict__ cell,
                                               const void* __restrict__ cello,
                                               const void* __restrict__ nmask,
                                               const void* __restrict__ emb,
                                               const void* __restrict__ fw1,
                                               const void* __restrict__ fb1,
                                               const void* __restrict__ fw2,
                                               const void* __restrict__ fb2,
                                               const void* __restrict__ in2f,
                                               const void* __restrict__ f2o,
                                               const void* __restrict__ den,
                                               const int* __restrict__ z,
                                               const int* __restrict__ nbrs,
                                               float* __restrict__ X,
                                               u32x2* __restrict__ DESC,
                                               u32* __restrict__ CNT,
                                               u16* __restrict__ WF,
                                               u32x2* __restrict__ TT,
                                               float* __restrict__ Y){
  __shared__ __align__(16) u16 Hb[4][16][168];
  int isbf = probe_bf(nmask);
  int bx = blockIdx.x, tid = threadIdx.x;
  int widx = tid>>6;
  int lane = tid & 63;
  int q = lane>>4, l15 = lane&15;

  if(bx < 96){
    // ---- table: self-build fw1/fw2 frags with HOISTED loads ----
    int wid = bx*4 + widx;           // 0..383
    int i  = wid>>7;
    int kb = (wid&127)*16;
    u16 (*H)[168] = Hb[widx];

    const float width = 5.0f/24.0f;
    const float c2 = (-0.5f/(width*width))*1.4426950408889634f;
    const float l2e = 1.4426950408889634f;
    float r = (float)(kb + l15) * (5.0f/(float)(NKNOT-1));

    float gv[8];
    #pragma unroll
    for(int j=0;j<8;j++){
      int k = q*8+j;
      if(k < 25){ float t = fmaf(-width,(float)k,r); gv[j] = fexp2(c2*t*t); }
      else gv[j] = (k==25) ? 1.f : 0.f;
    }
    union{ u32 d[4]; bf16x8 v; } afu;
    afu.d[0]=pk2(gv[0],gv[1]); afu.d[1]=pk2(gv[2],gv[3]);
    afu.d[2]=pk2(gv[4],gv[5]); afu.d[3]=pk2(gv[6],gv[7]);
    bf16x8 af = afu.v;

    f32x4 acc[8];
    #pragma unroll
    for(int th=0; th<2; ++th){
      float v[4][8];
      #pragma unroll
      for(int tt=0;tt<4;tt++){
        int c = (th*4+tt)*16 + l15;
        #pragma unroll
        for(int j=0;j<8;j++){
          int k = q*8+j;
          float x;
          if(k < 25)      x = ldin(fw1, (size_t)i*3200 + (size_t)k*128 + c, isbf);
          else if(k==25)  x = ldin(fb1, (size_t)i*128 + c, isbf);
          else            x = 0.f;
          v[tt][j] = x * l2e;
        }
      }
      #pragma unroll
      for(int tt=0;tt<4;tt++){
        union{ u32 d[4]; bf16x8 w; } wu;
        wu.d[0]=pk2(v[tt][0],v[tt][1]); wu.d[1]=pk2(v[tt][2],v[tt][3]);
        wu.d[2]=pk2(v[tt][4],v[tt][5]); wu.d[3]=pk2(v[tt][6],v[tt][7]);
        acc[th*4+tt] = mfma16(wu.w, af, (f32x4){0.f,0.f,0.f,0.f});
      }
    }
    const float ln2 = 0.69314718055994531f;
    #pragma unroll
    for(int t=0;t<8;t++){
      float h0 = fmaf(flog2(1.f+fexp2(acc[t][0])), ln2, -ln2);
      float h1 = fmaf(flog2(1.f+fexp2(acc[t][1])), ln2, -ln2);
      float h2 = fmaf(flog2(1.f+fexp2(acc[t][2])), ln2, -ln2);
      float h3 = fmaf(flog2(1.f+fexp2(acc[t][3])), ln2, -ln2);
      u32x2 d; d[0]=pk2(h0,h1); d[1]=pk2(h2,h3);
      *(u32x2*)(&H[l15][t*16 + q*4]) = d;
    }
    { // bias block cols 128..159: col128 = 1.0 (adds fb2), rest 0
      u32x2 zb; zb[0] = (q==0) ? pk2(1.f, 0.f) : 0u; zb[1] = 0u;
      *(u32x2*)(&H[l15][128 + q*4]) = zb;
      u32x2 zz; zz[0]=0u; zz[1]=0u;
      *(u32x2*)(&H[l15][144 + q*4]) = zz;
    }
    #pragma unroll
    for(int t=0;t<8;t++) acc[t] = (f32x4){0.f,0.f,0.f,0.f};
    #pragma unroll
    for(int kk=0;kk<5;kk++){
      bf16x8 a2 = *(const bf16x8*)(&H[l15][kk*32 + q*8]);
      #pragma unroll
      for(int th=0; th<2; ++th){
        float v[4][8];
        #pragma unroll
        for(int tt=0;tt<4;tt++){
          int c = (th*4+tt)*16 + l15;
          #pragma unroll
          for(int j=0;j<8;j++){
            int k = kk*32 + q*8 + j;
            float x;
            if(k < 128)      x = ldin(fw2, (size_t)i*16384 + (size_t)k*128 + c, isbf);
            else if(k==128)  x = ldin(fb2, (size_t)i*128 + c, isbf);
            else             x = 0.f;
            v[tt][j] = x;
          }
        }
        #pragma unroll
        for(int tt=0;tt<4;tt++){
          union{ u32 d[4]; bf16x8 w; } wu;
          wu.d[0]=pk2(v[tt][0],v[tt][1]); wu.d[1]=pk2(v[tt][2],v[tt][3]);
          wu.d[2]=pk2(v[tt][4],v[tt][5]); wu.d[3]=pk2(v[tt][6],v[tt][7]);
          acc[th*4+tt] = mfma16(a2, wu.w, acc[th*4+tt]);
        }
      }
    }
    {
      u32x2* ttb = TT + (size_t)i*NKNOT*64;
      int row = kb + l15;
      #pragma unroll
      for(int t=0;t<8;t++){
        u32 d0 = pk2(acc[t][0],acc[t][1]);
        u32 d1 = pk2(acc[t][2],acc[t][3]);
        int l = t*8 + q*2;
        ((u32*)&ttb[(size_t)row*64 + l    ])[0] = d0;
        ((u32*)&ttb[(size_t)row*64 + l + 1])[0] = d1;
        if(row > 0){
          ((u32*)&ttb[(size_t)(row-1)*64 + l    ])[1] = d0;
          ((u32*)&ttb[(size_t)(row-1)*64 + l + 1])[1] = d1;
        }
      }
    }
    return;
  }
  if(bx < 224){
    // ---- proj: y0 = emb[z] @ in2f[0], hoisted-load self-build ----
    int wid2 = (bx-96)*4 + widx;     // 0..511
    int row0 = wid2*16;
    int zr = z[row0 + l15];
    f32x4 acc[8];
    #pragma unroll
    for(int t=0;t<8;t++) acc[t] = (f32x4){0.f,0.f,0.f,0.f};
    #pragma unroll
    for(int kk=0;kk<4;kk++){
      bf16x8 xf;
      if(isbf) xf = *(const bf16x8*)((const u16*)emb + (size_t)zr*128 + kk*32 + q*8);
      else     xf = ldfragA_f32((const float*)emb + (size_t)zr*128 + kk*32 + q*8);
      #pragma unroll
      for(int th=0; th<2; ++th){
        float v[4][8];
        #pragma unroll
        for(int tt=0;tt<4;tt++){
          int c = (th*4+tt)*16 + l15;
          #pragma unroll
          for(int j=0;j<8;j++)
            v[tt][j] = ldin(in2f, (size_t)(kk*32+q*8+j)*128 + c, isbf);
        }
        #pragma unroll
        for(int tt=0;tt<4;tt++){
          union{ u32 d[4]; bf16x8 w; } wu;
          wu.d[0]=pk2(v[tt][0],v[tt][1]); wu.d[1]=pk2(v[tt][2],v[tt][3]);
          wu.d[2]=pk2(v[tt][4],v[tt][5]); wu.d[3]=pk2(v[tt][6],v[tt][7]);
          acc[th*4+tt] = mfma16(wu.w, xf, acc[th*4+tt]);
        }
      }
    }
    #pragma unroll
    for(int t=0;t<8;t++)
      *(f32x4*)(Y + (size_t)(row0+l15)*128 + t*16 + q*4) = acc[t];
    return;
  }
  if(bx < 1248){
    int idx = (bx-224)*256 + tid;              // < 8192*32
    int a = idx>>5, f4 = (idx&31)*4;
    f32x4 e = ldin4(emb, (size_t)z[a]*128 + f4, isbf);
    *(f32x4*)(X + (size_t)a*128 + f4) = e;
    return;
  }
  if(bx < 3296){
    int pairIdx = (bx-1248)*256 + tid;         // < 8192*64
    int atom = pairIdx>>6;
    int b = atom>>10;
    int nb = nbrs[pairIdx];
    int jrow = (b<<10) + nb;
    float pi0=ldin(pos,atom*3+0,isbf), pi1=ldin(pos,atom*3+1,isbf), pi2=ldin(pos,atom*3+2,isbf);
    float pj0=ldin(pos,jrow*3+0,isbf), pj1=ldin(pos,jrow*3+1,isbf), pj2=ldin(pos,jrow*3+2,isbf);
    float co0=ldin(cello,(size_t)pairIdx*3+0,isbf),
          co1=ldin(cello,(size_t)pairIdx*3+1,isbf),
          co2=ldin(cello,(size_t)pairIdx*3+2,isbf);
    size_t cb = (size_t)b*9;
    pj0 += co0*ldin(cell,cb+0,isbf) + co1*ldin(cell,cb+3,isbf) + co2*ldin(cell,cb+6,isbf);
    pj1 += co0*ldin(cell,cb+1,isbf) + co1*ldin(cell,cb+4,isbf) + co2*ldin(cell,cb+7,isbf);
    pj2 += co0*ldin(cell,cb+2,isbf) + co1*ldin(cell,cb+5,isbf) + co2*ldin(cell,cb+8,isbf);
    float d0 = pj0-pi0, d1 = pj1-pi1, d2 = pj2-pi2;
    float dd = d0*d0 + d1*d1 + d2*d2;
    float m  = ldin(nmask,pairIdx,isbf);
    float r  = sqrtf(m>0.f ? dd : 1.f) * m;
    float c  = 0.5f*(__cosf(r*3.14159265358979f/5.f)+1.f) * ((r<5.f)?1.f:0.f) * m;
    float s  = r * ((float)(NKNOT-1)/5.0f);
    int   k  = (int)s; if(k > NKNOT-2) k = NKNOT-2;
    float fr = s - (float)k;
    float a0 = c*(1.f-fr), a1 = c*fr;
    union{ _Float16 h[2]; u32 u; } pa;
    pa.h[0] = (_Float16)a0; pa.h[1] = (_Float16)a1;
    int lane2 = tid & 63;
    int act = (c > 0.f);
    u64 bal = __ballot(act);
    u64 below = bal & ((1ULL<<lane2)-1ULL);
    int cnt = (int)__popcll(bal);
    int apre = (int)__popcll(below);
    int pos_ = act ? apre : (cnt + (lane2 - apre));
    u32x2 dsc;
    if(act){ dsc[0] = pa.u; dsc[1] = (u32)k | ((u32)nb<<16); }
    else   { dsc[0] = 0u;   dsc[1] = 0u; }
    DESC[(size_t)atom*64 + pos_] = dsc;
    if(lane2 == 0) CNT[atom] = (u32)cnt;
    return;
  }
  // ---- wfrag: wid in [0,288) = 3 interactions x {in2f,f2o,den} x 32 frags
  {
    int wid = (bx-3296)*4 + widx;
    int i = wid/96, r = wid%96;
    int mat = r>>5, kk = (r>>3)&3, t = r&7;
    const void* src; int off;
    switch(mat){
      case 0:  src = in2f; off=WF_IN2F; break;
      case 1:  src = f2o;  off=WF_F2O;  break;
      default: src = den;  off=WF_DEN;  break;
    }
    size_t sbase = (size_t)i*16384;
    int c = t*16 + l15;
    bf16x8 frag;
    #pragma unroll
    for(int j=0;j<8;j++){
      int k = kk*32 + q*8 + j;
      frag[j] = (short)f2b(ldin(src, sbase + (size_t)k*128 + c, isbf));
    }
    *(bf16x8*)(WF + (size_t)i*WF_STRIDE + off + ((kk*8+t)*64 + lane)*8) = frag;
  }
}

// ---------------------------------------------------------------------------
// Per-batch counting sort of atoms by active-pair count -> PERM.
// Blocks = 8 (one per batch).  Sorted-contiguous groups of 8 go to one
// k_iter block, so each block's straggler max ~= its own quantile.
// Intra-bin order is nondeterministic (atomicAdd) but numerically irrelevant:
// atoms are independent; output locations depend only on atom id.
__global__ __launch_bounds__(256) void k_sort(const u32* __restrict__ CNT,
                                              int* __restrict__ PERM){
  __shared__ u32 hist[65];
  __shared__ u32 pref[65];
  int b = blockIdx.x;
  int tid = threadIdx.x;
  if(tid < 65) hist[tid] = 0;
  __syncthreads();
  for(int a = tid; a < 1024; a += 256)
    atomicAdd(&hist[CNT[b*1024 + a]], 1u);
  __syncthreads();
  if(tid == 0){
    u32 s = 0;
    for(int i=0;i<65;i++){ pref[i] = s; s += hist[i]; }
  }
  __syncthreads();
  for(int a = tid; a < 1024; a += 256){
    u32 c = CNT[b*1024 + a];
    u32 r = atomicAdd(&pref[c], 1u);
    PERM[b*1024 + r] = b*1024 + a;     // global atom id
  }
}

// ---------------------------------------------------------------------------
// Fused iteration (R12 loop structure) over PERMUTED atoms: block handles 8
// count-sorted atoms -> balanced straggler max.  512 thr = 8 waves; grid 1024.
__global__ __launch_bounds__(512, 8) void k_iter(const u32x2* __restrict__ desc,
                                                 const u32* __restrict__ CNT,
                                                 const int* __restrict__ PERM,
                                                 const u32x2* __restrict__ TT,
                                                 const float* __restrict__ Yr,
                                                 float* __restrict__ X,
                                                 float* __restrict__ Yw,
                                                 const u16* __restrict__ f2of,
                                                 const u16* __restrict__ denf,
                                                 const u16* __restrict__ in2fN,
                                                 const void* __restrict__ f2ob,
                                                 const void* __restrict__ denb,
                                                 const void* __restrict__ nmask,
                                                 void* __restrict__ OUT,
                                                 int last, int iidx){
  __shared__ __align__(16) float AGGs[16][132];
  __shared__ __align__(16) u16 Tb[16][136];
  __shared__ __align__(16) u16 Xw[16][136];
  int isbf = probe_bf(nmask);
  int widx = threadIdx.x>>6;        // 0..7
  int lane = threadIdx.x & 63;
  int q = lane>>4, l15 = lane&15;
  int bid = blockIdx.x;
  int base = (bid & 7)*1024 + (bid >> 3)*8;   // 8 sorted ranks/block, batch=bid%8

  // ---- Phase 1: CFConv over active pairs, half-wave per pair.
  {
    int atom = PERM[base + widx];
    int cnt = (int)__builtin_amdgcn_readfirstlane(CNT[atom]);
    int ng  = (cnt + 3) >> 2;                    // chunks of 4 pairs
    u32x2 dsc = desc[(size_t)atom*64 + lane];    // lane p holds desc of slot p
    const char* Yb = (const char*)(Yr + (size_t)(atom & ~1023)*128);
    const char* Tc = (const char*)TT;
    int h   = lane>>5;                            // half index: pair parity
    int j32 = lane&31;                            // filters 4*j32 .. 4*j32+3
    int boff = j32<<4;                            // 16 B per lane
    f32x4 acc4 = (f32x4){0.f,0.f,0.f,0.f};
    #pragma unroll 1
    for(int g=0; g<ng; ++g){                      // 4 pairs per g (2 load steps)
      u32 cu[2]; u32x4 tt[2]; f32x4 yv[2];
      #pragma unroll
      for(int s=0; s<2; ++s){
        int p0 = g*4 + s*2;
        u32 d1a = __builtin_amdgcn_readlane(dsc[1], p0);
        u32 d1b = __builtin_amdgcn_readlane(dsc[1], p0+1);
        u32 d0a = __builtin_amdgcn_readlane(dsc[0], p0);
        u32 d0b = __builtin_amdgcn_readlane(dsc[0], p0+1);
        u32 d1 = h ? d1b : d1a;
        cu[s]  = h ? d0b : d0a;
        u32 krow = d1 & 0xffffu;
        u32 nbr  = d1 >> 16;
        tt[s] = *(const u32x4*)(Tc + ((size_t)krow<<9) + boff);
        yv[s] = *(const f32x4*)(Yb + ((size_t)nbr<<9) + boff);
      }
      #pragma unroll
      for(int s=0; s<2; ++s){
        union{ u32 u; _Float16 hh[2]; } pa; pa.u = cu[s];
        float a0 = (float)pa.hh[0], a1 = (float)pa.hh[1];
        float w0 = fmaf(a1, asf(tt[s][1]<<16),          a0*asf(tt[s][0]<<16));
        float w1 = fmaf(a1, asf(tt[s][1]&0xffff0000u),  a0*asf(tt[s][0]&0xffff0000u));
        float w2 = fmaf(a1, asf(tt[s][3]<<16),          a0*asf(tt[s][2]<<16));
        float w3 = fmaf(a1, asf(tt[s][3]&0xffff0000u),  a0*asf(tt[s][2]&0xffff0000u));
        acc4[0] = fmaf(w0, yv[s][0], acc4[0]);
        acc4[1] = fmaf(w1, yv[s][1], acc4[1]);
        acc4[2] = fmaf(w2, yv[s][2], acc4[2]);
        acc4[3] = fmaf(w3, yv[s][3], acc4[3]);
      }
    }
    *(f32x4*)(&AGGs[widx + 8*h][j32*4]) = acc4;   // partials: rows a / a+8
  }
  __syncthreads();

  // ---- Phase 2: v = ssp(agg @ f2out + b); t = widx; merge halves via shfl.
  {
    int t = widx;
    f32x4 acc = (f32x4){0.f,0.f,0.f,0.f};
    #pragma unroll
    for(int kk=0;kk<4;kk++){
      bf16x8 gf = ldfragA_f32(&AGGs[l15][kk*32 + q*8]);
      bf16x8 wv = *(const bf16x8*)(f2of + ((kk*8+t)*64 + lane)*8);
      acc = mfma16(wv, gf, acc);
    }
    #pragma unroll
    for(int r=0;r<4;r++) acc[r] += __shfl_xor(acc[r], 8);
    f32x4 bv = ldin4(f2ob, (size_t)iidx*128 + t*16 + q*4, isbf);
    u32x2 d;
    d[0] = pk2(sspf(acc[0]+bv[0]), sspf(acc[1]+bv[1]));
    d[1] = pk2(sspf(acc[2]+bv[2]), sspf(acc[3]+bv[3]));
    *(u32x2*)(&Tb[l15][t*16 + q*4]) = d;   // rows 8-15 duplicate rows 0-7
  }
  __syncthreads();

  // ---- Phase 2b: dense @ + bias + X residual; rows via PERM (clamped).
  int arow = PERM[base + (l15 & 7)];       // lanes 8-15 duplicate 0-7 (discarded)
  {
    int t = widx;
    f32x4 acc = (f32x4){0.f,0.f,0.f,0.f};
    #pragma unroll
    for(int kk=0;kk<4;kk++){
      bf16x8 tf = *(const bf16x8*)(&Tb[l15][kk*32 + q*8]);
      bf16x8 wv = *(const bf16x8*)(denf + ((kk*8+t)*64 + lane)*8);
      acc = mfma16(wv, tf, acc);
    }
    size_t idx = (size_t)arow*128 + t*16 + q*4;
    f32x4 bv = ldin4(denb, (size_t)iidx*128 + t*16 + q*4, isbf);
    f32x4 xv = *(const f32x4*)(X + idx);
    f32x4 xn;
    #pragma unroll
    for(int r=0;r<4;r++) xn[r] = xv[r] + acc[r] + bv[r];
    if(l15 < 8){
      *(f32x4*)(X + idx) = xn;
      if(last){
        if(isbf){
          u32x2 o; o[0]=pk2(xn[0],xn[1]); o[1]=pk2(xn[2],xn[3]);
          *(u32x2*)((u16*)OUT + idx) = o;
        } else {
          *(f32x4*)((float*)OUT + idx) = xn;
        }
      }
    }
    if(!last){
      u32x2 d; d[0]=pk2(xn[0],xn[1]); d[1]=pk2(xn[2],xn[3]);
      *(u32x2*)(&Xw[l15][t*16 + q*4]) = d;
    }
  }
  if(!last){
    __syncthreads();
    // ---- Phase 3: y_next = x_new @ in2f_next; rows via PERM, l15<8 stores.
    {
      int t = widx;
      f32x4 acc = (f32x4){0.f,0.f,0.f,0.f};
      #pragma unroll
      for(int kk=0;kk<4;kk++){
        bf16x8 xf = *(const bf16x8*)(&Xw[l15][kk*32 + q*8]);
        bf16x8 wv = *(const bf16x8*)(in2fN + ((kk*8+t)*64 + lane)*8);
        acc = mfma16(wv, xf, acc);
      }
      if(l15 < 8)
        *(f32x4*)(Yw + (size_t)arow*128 + t*16 + q*4) = acc;
    }
  }
}

// ---------------------------------------------------------------------------
extern "C" void kernel_launch(void* const* d_in, const int* in_sizes, int n_in,
                              void* d_out, int out_size, void* d_ws, size_t ws_size,
                              hipStream_t stream){
  const void* pos   = d_in[0];
  const void* cell  = d_in[1];
  const void* cello = d_in[2];
  const void* nmask = d_in[3];
  // d_in[4] atom_mask: unused by the output
  const void* emb   = d_in[5];
  const void* fw1   = d_in[6];
  const void* fb1   = d_in[7];
  const void* fw2   = d_in[8];
  const void* fb2   = d_in[9];
  const void* in2f  = d_in[10];
  const void* f2o   = d_in[11];
  const void* f2ob  = d_in[12];
  const void* den   = d_in[13];
  const void* denb  = d_in[14];
  const int* z      = (const int*)d_in[15];
  const int* nbrs   = (const int*)d_in[16];

  char* ws = (char*)d_ws;
  float* X    = (float*)(ws);                 //  4 MB fp32 features
  float* Y    = (float*)(ws +  4194304);      //  4 MB projected features (ping)
  float* Y2   = (float*)(ws +  8388608);      //  4 MB projected features (pong)
  u32x2* DESC = (u32x2*)(ws + 12582912);      //  4 MB pair descriptors
  u16*   WF   = (u16*)  (ws + 16777216);      // 432 KB weight B-frags
  u32x2* TT   = (u32x2*)(ws + 17301504);      //  3 MB interleaved knot-pair table
  u32*   CNT  = (u32*)  (ws + 20447232);      // 32 KB per-atom active counts
  int*   PERM = (int*)  (ws + 20480000);      // 32 KB count-sorted atom order

  k_setup<<<3368, 256, 0, stream>>>(pos, cell, cello, nmask, emb,
                                    fw1, fb1, fw2, fb2, in2f, f2o, den,
                                    z, nbrs, X, DESC, CNT, WF, TT, Y);
  k_sort <<<   8, 256, 0, stream>>>(CNT, PERM);

  for(int i=0;i<3;i++){
    const u16* base = WF + (size_t)i*WF_STRIDE;
    const u16* in2fN = (i<2) ? (WF + (size_t)(i+1)*WF_STRIDE + WF_IN2F) : WF;
    const float* Yrd = (i&1) ? Y2 : Y;
    float*       Ywr = (i&1) ? Y  : Y2;
    k_iter<<<1024, 512, 0, stream>>>(DESC, CNT, PERM, TT + (size_t)i*NKNOT*64,
                                     Yrd, X, Ywr,
                                     base + WF_F2O, base + WF_DEN, in2fN,
                                     f2ob, denb, nmask,
                                     d_out, (i==2) ? 1 : 0, i);
  }
}

// Round 17
// 160.233 us; speedup vs baseline: 1.2973x; 1.0428x over previous
//
#include <hip/hip_runtime.h>

typedef __attribute__((ext_vector_type(8))) short bf16x8;
typedef __attribute__((ext_vector_type(4))) float f32x4;
typedef __attribute__((ext_vector_type(2))) unsigned int u32x2;
typedef __attribute__((ext_vector_type(4))) unsigned int u32x4;
typedef __attribute__((ext_vector_type(2))) __bf16 bf16x2t;
typedef unsigned short u16;
typedef unsigned int u32;
typedef unsigned long long u64;

#define DI __device__ __forceinline__

// Problem constants: B=8, A=1024, NB=64, NAB=NF=128, NG=25, NI=3
#define NKNOT 2048

DI float b2f(u16 u){ union{u32 i; float f;} v; v.i = ((u32)u)<<16; return v.f; }
DI float asf(u32 u){ union{u32 i; float f;} v; v.i = u; return v.f; }
DI u16 f2b(float f){ union{float f; u32 i;} v; v.f=f; u32 u=v.i;
                     return (u16)((u + 0x7fffu + ((u>>16)&1u))>>16); }
DI u32 pk2(float lo, float hi){
#if __has_builtin(__builtin_amdgcn_cvt_pk_bf16_f32)
  bf16x2t h = __builtin_amdgcn_cvt_pk_bf16_f32(lo, hi);
  u32 d; __builtin_memcpy(&d, &h, 4); return d;
#else
  return (u32)f2b(lo) | ((u32)f2b(hi)<<16);
#endif
}
DI float fexp2(float x){
#if __has_builtin(__builtin_amdgcn_exp2f)
  return __builtin_amdgcn_exp2f(x);
#else
  return __expf(x*0.6931471805599453f);
#endif
}
DI float flog2(float x){
#if __has_builtin(__builtin_amdgcn_logf)
  return __builtin_amdgcn_logf(x);
#else
  return __logf(x)*1.4426950408889634f;
#endif
}
DI float ldin(const void* p, size_t i, int isbf){
  return isbf ? b2f(((const u16*)p)[i]) : ((const float*)p)[i];
}
DI f32x4 ldin4(const void* p, size_t i, int isbf){
  if(isbf){
    u32x2 d = *(const u32x2*)((const u16*)p + i);
    f32x4 r;
    r[0] = b2f((u16)(d[0]&0xffff)); r[1] = b2f((u16)(d[0]>>16));
    r[2] = b2f((u16)(d[1]&0xffff)); r[3] = b2f((u16)(d[1]>>16));
    return r;
  }
  return *(const f32x4*)((const float*)p + i);
}
DI int probe_bf(const void* nmask){ return ((const u16*)nmask)[0] == 0x3F80u; }

DI f32x4 mfma16(bf16x8 a, bf16x8 b, f32x4 c){
  return __builtin_amdgcn_mfma_f32_16x16x32_bf16(a,b,c,0,0,0);
}
DI bf16x8 ldfragA_f32(const float* p){
  f32x4 a = ((const f32x4*)p)[0], b = ((const f32x4*)p)[1];
  union{ u32 d[4]; bf16x8 v; } u;
  u.d[0]=pk2(a[0],a[1]); u.d[1]=pk2(a[2],a[3]);
  u.d[2]=pk2(b[0],b[1]); u.d[3]=pk2(b[2],b[3]);
  return u.v;
}
DI float sspf(float x){ return __logf(1.f + __expf(x)) - 0.6931471805599453f; }

// WF layout per interaction (u16 offsets; frag = 512 u16):
//   in2f frags off 24576 | f2o off 40960 | dense off 57344
// (fw1/fw2 regions unused: table blocks self-build from raw weights)
#define WF_STRIDE 73728
#define WF_IN2F   24576
#define WF_F2O    40960
#define WF_DEN    57344

// Block ranges in the merged setup kernel (slow blocks FIRST so they start
// at t=0 and overlap the wide embed/desc phases instead of forming a tail):
//   [0,96)       table: TT from raw fw1/fb1/fw2/fb2 (hoisted-load self-build)
//   [96,224)     proj:  Y = emb[z] @ in2f[0] (hoisted-load self-build)
//   [224,1248)   embed: X = emb[z]
//   [1248,3296)  dist -> desc (ballot-compacted) + CNT
//   [3296,3368)  wfrag: in2f/f2o/dense B-frags for k_iter
__global__ __launch_bounds__(256) void k_setup(const void* __restrict__ pos,
                                               const void* __restrict__ cell,
                                               const void* __restrict__ cello,
                                               const void* __restrict__ nmask,
                                               const void* __restrict__ emb,
                                               const void* __restrict__ fw1,
                                               const void* __restrict__ fb1,
                                               const void* __restrict__ fw2,
                                               const void* __restrict__ fb2,
                                               const void* __restrict__ in2f,
                                               const void* __restrict__ f2o,
                                               const void* __restrict__ den,
                                               const int* __restrict__ z,
                                               const int* __restrict__ nbrs,
                                               float* __restrict__ X,
                                               u32x2* __restrict__ DESC,
                                               u32* __restrict__ CNT,
                                               u16* __restrict__ WF,
                                               u32x2* __restrict__ TT,
                                               float* __restrict__ Y){
  __shared__ __align__(16) u16 Hb[4][16][168];
  int isbf = probe_bf(nmask);
  int bx = blockIdx.x, tid = threadIdx.x;
  int widx = tid>>6;
  int lane = tid & 63;
  int q = lane>>4, l15 = lane&15;

  if(bx < 96){
    // ---- table: self-build fw1/fw2 frags with HOISTED loads ----
    int wid = bx*4 + widx;           // 0..383
    int i  = wid>>7;
    int kb = (wid&127)*16;
    u16 (*H)[168] = Hb[widx];

    const float width = 5.0f/24.0f;
    const float c2 = (-0.5f/(width*width))*1.4426950408889634f;
    const float l2e = 1.4426950408889634f;
    float r = (float)(kb + l15) * (5.0f/(float)(NKNOT-1));

    float gv[8];
    #pragma unroll
    for(int j=0;j<8;j++){
      int k = q*8+j;
      if(k < 25){ float t = fmaf(-width,(float)k,r); gv[j] = fexp2(c2*t*t); }
      else gv[j] = (k==25) ? 1.f : 0.f;
    }
    union{ u32 d[4]; bf16x8 v; } afu;
    afu.d[0]=pk2(gv[0],gv[1]); afu.d[1]=pk2(gv[2],gv[3]);
    afu.d[2]=pk2(gv[4],gv[5]); afu.d[3]=pk2(gv[6],gv[7]);
    bf16x8 af = afu.v;

    f32x4 acc[8];
    // fw1 pass: rows k=q*8+j (<25 -> fw1*log2e, ==25 -> fb1*log2e, else 0)
    #pragma unroll
    for(int th=0; th<2; ++th){
      float v[4][8];
      #pragma unroll
      for(int tt=0;tt<4;tt++){
        int c = (th*4+tt)*16 + l15;
        #pragma unroll
        for(int j=0;j<8;j++){
          int k = q*8+j;
          float x;
          if(k < 25)      x = ldin(fw1, (size_t)i*3200 + (size_t)k*128 + c, isbf);
          else if(k==25)  x = ldin(fb1, (size_t)i*128 + c, isbf);
          else            x = 0.f;
          v[tt][j] = x * l2e;
        }
      }
      #pragma unroll
      for(int tt=0;tt<4;tt++){
        union{ u32 d[4]; bf16x8 w; } wu;
        wu.d[0]=pk2(v[tt][0],v[tt][1]); wu.d[1]=pk2(v[tt][2],v[tt][3]);
        wu.d[2]=pk2(v[tt][4],v[tt][5]); wu.d[3]=pk2(v[tt][6],v[tt][7]);
        acc[th*4+tt] = mfma16(wu.w, af, (f32x4){0.f,0.f,0.f,0.f});
      }
    }
    const float ln2 = 0.69314718055994531f;
    #pragma unroll
    for(int t=0;t<8;t++){
      float h0 = fmaf(flog2(1.f+fexp2(acc[t][0])), ln2, -ln2);
      float h1 = fmaf(flog2(1.f+fexp2(acc[t][1])), ln2, -ln2);
      float h2 = fmaf(flog2(1.f+fexp2(acc[t][2])), ln2, -ln2);
      float h3 = fmaf(flog2(1.f+fexp2(acc[t][3])), ln2, -ln2);
      u32x2 d; d[0]=pk2(h0,h1); d[1]=pk2(h2,h3);
      *(u32x2*)(&H[l15][t*16 + q*4]) = d;
    }
    { // bias block cols 128..159: col128 = 1.0 (adds fb2), rest 0
      u32x2 zb; zb[0] = (q==0) ? pk2(1.f, 0.f) : 0u; zb[1] = 0u;
      *(u32x2*)(&H[l15][128 + q*4]) = zb;
      u32x2 zz; zz[0]=0u; zz[1]=0u;
      *(u32x2*)(&H[l15][144 + q*4]) = zz;
    }
    #pragma unroll
    for(int t=0;t<8;t++) acc[t] = (f32x4){0.f,0.f,0.f,0.f};
    // fw2 pass: rows k=kk*32+q*8+j (<128 -> fw2, ==128 -> fb2, else 0)
    #pragma unroll
    for(int kk=0;kk<5;kk++){
      bf16x8 a2 = *(const bf16x8*)(&H[l15][kk*32 + q*8]);
      #pragma unroll
      for(int th=0; th<2; ++th){
        float v[4][8];
        #pragma unroll
        for(int tt=0;tt<4;tt++){
          int c = (th*4+tt)*16 + l15;
          #pragma unroll
          for(int j=0;j<8;j++){
            int k = kk*32 + q*8 + j;
            float x;
            if(k < 128)      x = ldin(fw2, (size_t)i*16384 + (size_t)k*128 + c, isbf);
            else if(k==128)  x = ldin(fb2, (size_t)i*128 + c, isbf);
            else             x = 0.f;
            v[tt][j] = x;
          }
        }
        #pragma unroll
        for(int tt=0;tt<4;tt++){
          union{ u32 d[4]; bf16x8 w; } wu;
          wu.d[0]=pk2(v[tt][0],v[tt][1]); wu.d[1]=pk2(v[tt][2],v[tt][3]);
          wu.d[2]=pk2(v[tt][4],v[tt][5]); wu.d[3]=pk2(v[tt][6],v[tt][7]);
          acc[th*4+tt] = mfma16(a2, wu.w, acc[th*4+tt]);
        }
      }
    }
    // store interleaved: row -> TT[row].slot0, TT[row-1].slot1
    {
      u32x2* ttb = TT + (size_t)i*NKNOT*64;
      int row = kb + l15;
      #pragma unroll
      for(int t=0;t<8;t++){
        u32 d0 = pk2(acc[t][0],acc[t][1]);
        u32 d1 = pk2(acc[t][2],acc[t][3]);
        int l = t*8 + q*2;
        ((u32*)&ttb[(size_t)row*64 + l    ])[0] = d0;
        ((u32*)&ttb[(size_t)row*64 + l + 1])[0] = d1;
        if(row > 0){
          ((u32*)&ttb[(size_t)(row-1)*64 + l    ])[1] = d0;
          ((u32*)&ttb[(size_t)(row-1)*64 + l + 1])[1] = d1;
        }
      }
    }
    return;
  }
  if(bx < 224){
    // ---- proj: y0 = emb[z] @ in2f[0], hoisted-load self-build ----
    int wid2 = (bx-96)*4 + widx;     // 0..511
    int row0 = wid2*16;
    int zr = z[row0 + l15];
    f32x4 acc[8];
    #pragma unroll
    for(int t=0;t<8;t++) acc[t] = (f32x4){0.f,0.f,0.f,0.f};
    #pragma unroll
    for(int kk=0;kk<4;kk++){
      bf16x8 xf;
      if(isbf) xf = *(const bf16x8*)((const u16*)emb + (size_t)zr*128 + kk*32 + q*8);
      else     xf = ldfragA_f32((const float*)emb + (size_t)zr*128 + kk*32 + q*8);
      #pragma unroll
      for(int th=0; th<2; ++th){
        float v[4][8];
        #pragma unroll
        for(int tt=0;tt<4;tt++){
          int c = (th*4+tt)*16 + l15;
          #pragma unroll
          for(int j=0;j<8;j++)
            v[tt][j] = ldin(in2f, (size_t)(kk*32+q*8+j)*128 + c, isbf);
        }
        #pragma unroll
        for(int tt=0;tt<4;tt++){
          union{ u32 d[4]; bf16x8 w; } wu;
          wu.d[0]=pk2(v[tt][0],v[tt][1]); wu.d[1]=pk2(v[tt][2],v[tt][3]);
          wu.d[2]=pk2(v[tt][4],v[tt][5]); wu.d[3]=pk2(v[tt][6],v[tt][7]);
          acc[th*4+tt] = mfma16(wu.w, xf, acc[th*4+tt]);
        }
      }
    }
    #pragma unroll
    for(int t=0;t<8;t++)
      *(f32x4*)(Y + (size_t)(row0+l15)*128 + t*16 + q*4) = acc[t];
    return;
  }
  if(bx < 1248){
    int idx = (bx-224)*256 + tid;              // < 8192*32
    int a = idx>>5, f4 = (idx&31)*4;
    f32x4 e = ldin4(emb, (size_t)z[a]*128 + f4, isbf);
    *(f32x4*)(X + (size_t)a*128 + f4) = e;
    return;
  }
  if(bx < 3296){
    int pairIdx = (bx-1248)*256 + tid;         // < 8192*64
    int atom = pairIdx>>6;
    int b = atom>>10;
    int nb = nbrs[pairIdx];
    int jrow = (b<<10) + nb;
    float pi0=ldin(pos,atom*3+0,isbf), pi1=ldin(pos,atom*3+1,isbf), pi2=ldin(pos,atom*3+2,isbf);
    float pj0=ldin(pos,jrow*3+0,isbf), pj1=ldin(pos,jrow*3+1,isbf), pj2=ldin(pos,jrow*3+2,isbf);
    float co0=ldin(cello,(size_t)pairIdx*3+0,isbf),
          co1=ldin(cello,(size_t)pairIdx*3+1,isbf),
          co2=ldin(cello,(size_t)pairIdx*3+2,isbf);
    size_t cb = (size_t)b*9;
    pj0 += co0*ldin(cell,cb+0,isbf) + co1*ldin(cell,cb+3,isbf) + co2*ldin(cell,cb+6,isbf);
    pj1 += co0*ldin(cell,cb+1,isbf) + co1*ldin(cell,cb+4,isbf) + co2*ldin(cell,cb+7,isbf);
    pj2 += co0*ldin(cell,cb+2,isbf) + co1*ldin(cell,cb+5,isbf) + co2*ldin(cell,cb+8,isbf);
    float d0 = pj0-pi0, d1 = pj1-pi1, d2 = pj2-pi2;
    float dd = d0*d0 + d1*d1 + d2*d2;
    float m  = ldin(nmask,pairIdx,isbf);
    float r  = sqrtf(m>0.f ? dd : 1.f) * m;
    float c  = 0.5f*(__cosf(r*3.14159265358979f/5.f)+1.f) * ((r<5.f)?1.f:0.f) * m;
    float s  = r * ((float)(NKNOT-1)/5.0f);
    int   k  = (int)s; if(k > NKNOT-2) k = NKNOT-2;
    float fr = s - (float)k;
    float a0 = c*(1.f-fr), a1 = c*fr;
    union{ _Float16 h[2]; u32 u; } pa;
    pa.h[0] = (_Float16)a0; pa.h[1] = (_Float16)a1;
    // ballot-compact: active pairs -> [0,cnt), zero-descs -> [cnt,64)
    int lane2 = tid & 63;
    int act = (c > 0.f);
    u64 bal = __ballot(act);
    u64 below = bal & ((1ULL<<lane2)-1ULL);
    int cnt = (int)__popcll(bal);
    int apre = (int)__popcll(below);
    int pos_ = act ? apre : (cnt + (lane2 - apre));
    u32x2 dsc;
    if(act){ dsc[0] = pa.u; dsc[1] = (u32)k | ((u32)nb<<16); }
    else   { dsc[0] = 0u;   dsc[1] = 0u; }
    DESC[(size_t)atom*64 + pos_] = dsc;
    if(lane2 == 0) CNT[atom] = (u32)cnt;
    return;
  }
  // ---- wfrag: wid in [0,288) = 3 interactions x {in2f,f2o,den} x 32 frags
  {
    int wid = (bx-3296)*4 + widx;
    int i = wid/96, r = wid%96;
    int mat = r>>5, kk = (r>>3)&3, t = r&7;
    const void* src; int off;
    switch(mat){
      case 0:  src = in2f; off=WF_IN2F; break;
      case 1:  src = f2o;  off=WF_F2O;  break;
      default: src = den;  off=WF_DEN;  break;
    }
    size_t sbase = (size_t)i*16384;
    int c = t*16 + l15;
    bf16x8 frag;
    #pragma unroll
    for(int j=0;j<8;j++){
      int k = kk*32 + q*8 + j;
      frag[j] = (short)f2b(ldin(src, sbase + (size_t)k*128 + c, isbf));
    }
    *(bf16x8*)(WF + (size_t)i*WF_STRIDE + off + ((kk*8+t)*64 + lane)*8) = frag;
  }
}

// ---------------------------------------------------------------------------
// Fused iteration: half-wave gather over compacted active pairs.
// 512 thr = 8 waves = 8 atoms/block; grid 1024 = 4 blocks/CU, co-resident.
// Phase 1 loops ceil(cnt/4) chunks of 4 pairs (depth-2 staging, half-wave per
// pair, dwordx4 TT + dwordx4 Y loads); dead pairs skipped (exact zeros).
__global__ __launch_bounds__(512, 8) void k_iter(const u32x2* __restrict__ desc,
                                                 const u32* __restrict__ CNT,
                                                 const u32x2* __restrict__ TT,
                                                 const float* __restrict__ Yr,
                                                 float* __restrict__ X,
                                                 float* __restrict__ Yw,
                                                 const u16* __restrict__ f2of,
                                                 const u16* __restrict__ denf,
                                                 const u16* __restrict__ in2fN,
                                                 const void* __restrict__ f2ob,
                                                 const void* __restrict__ denb,
                                                 const void* __restrict__ nmask,
                                                 void* __restrict__ OUT,
                                                 int last, int iidx){
  __shared__ __align__(16) float AGGs[16][132];
  __shared__ __align__(16) u16 Tb[16][136];
  __shared__ __align__(16) u16 Xw[16][136];
  int isbf = probe_bf(nmask);
  int widx = threadIdx.x>>6;        // 0..7
  int lane = threadIdx.x & 63;
  int q = lane>>4, l15 = lane&15;
  int bid = blockIdx.x;
  int row0 = (bid & 7)*1024 + (bid >> 3)*8;   // 8 atoms/block, batch = bid%8

  // ---- Phase 1: CFConv over active pairs, half-wave per pair.
  {
    int atom = row0 + widx;
    int cnt = (int)__builtin_amdgcn_readfirstlane(CNT[atom]);
    int ng  = (cnt + 3) >> 2;                    // chunks of 4 pairs
    u32x2 dsc = desc[(size_t)atom*64 + lane];    // lane p holds desc of slot p
    const char* Yb = (const char*)(Yr + (size_t)(atom & ~1023)*128);
    const char* Tc = (const char*)TT;
    int h   = lane>>5;                            // half index: pair parity
    int j32 = lane&31;                            // filters 4*j32 .. 4*j32+3
    int boff = j32<<4;                            // 16 B per lane
    f32x4 acc4 = (f32x4){0.f,0.f,0.f,0.f};
    #pragma unroll 1
    for(int g=0; g<ng; ++g){                      // 4 pairs per g (2 load steps)
      u32 cu[2]; u32x4 tt[2]; f32x4 yv[2];
      #pragma unroll
      for(int s=0; s<2; ++s){
        int p0 = g*4 + s*2;
        u32 d1a = __builtin_amdgcn_readlane(dsc[1], p0);
        u32 d1b = __builtin_amdgcn_readlane(dsc[1], p0+1);
        u32 d0a = __builtin_amdgcn_readlane(dsc[0], p0);
        u32 d0b = __builtin_amdgcn_readlane(dsc[0], p0+1);
        u32 d1 = h ? d1b : d1a;
        cu[s]  = h ? d0b : d0a;
        u32 krow = d1 & 0xffffu;
        u32 nbr  = d1 >> 16;
        tt[s] = *(const u32x4*)(Tc + ((size_t)krow<<9) + boff);
        yv[s] = *(const f32x4*)(Yb + ((size_t)nbr<<9) + boff);
      }
      #pragma unroll
      for(int s=0; s<2; ++s){
        union{ u32 u; _Float16 hh[2]; } pa; pa.u = cu[s];
        float a0 = (float)pa.hh[0], a1 = (float)pa.hh[1];
        float w0 = fmaf(a1, asf(tt[s][1]<<16),          a0*asf(tt[s][0]<<16));
        float w1 = fmaf(a1, asf(tt[s][1]&0xffff0000u),  a0*asf(tt[s][0]&0xffff0000u));
        float w2 = fmaf(a1, asf(tt[s][3]<<16),          a0*asf(tt[s][2]<<16));
        float w3 = fmaf(a1, asf(tt[s][3]&0xffff0000u),  a0*asf(tt[s][2]&0xffff0000u));
        acc4[0] = fmaf(w0, yv[s][0], acc4[0]);
        acc4[1] = fmaf(w1, yv[s][1], acc4[1]);
        acc4[2] = fmaf(w2, yv[s][2], acc4[2]);
        acc4[3] = fmaf(w3, yv[s][3], acc4[3]);
      }
    }
    *(f32x4*)(&AGGs[widx + 8*h][j32*4]) = acc4;   // partials: rows a / a+8
  }
  __syncthreads();

  // ---- Phase 2: v = ssp(agg @ f2out + b); t = widx; merge halves via shfl.
  {
    int t = widx;
    f32x4 acc = (f32x4){0.f,0.f,0.f,0.f};
    #pragma unroll
    for(int kk=0;kk<4;kk++){
      bf16x8 gf = ldfragA_f32(&AGGs[l15][kk*32 + q*8]);
      bf16x8 wv = *(const bf16x8*)(f2of + ((kk*8+t)*64 + lane)*8);
      acc = mfma16(wv, gf, acc);
    }
    #pragma unroll
    for(int r=0;r<4;r++) acc[r] += __shfl_xor(acc[r], 8);
    f32x4 bv = ldin4(f2ob, (size_t)iidx*128 + t*16 + q*4, isbf);
    u32x2 d;
    d[0] = pk2(sspf(acc[0]+bv[0]), sspf(acc[1]+bv[1]));
    d[1] = pk2(sspf(acc[2]+bv[2]), sspf(acc[3]+bv[3]));
    *(u32x2*)(&Tb[l15][t*16 + q*4]) = d;   // rows 8-15 duplicate rows 0-7
  }
  __syncthreads();

  // ---- Phase 2b: dense @ + bias + X residual; stores guarded to l15<8.
  {
    int t = widx;
    f32x4 acc = (f32x4){0.f,0.f,0.f,0.f};
    #pragma unroll
    for(int kk=0;kk<4;kk++){
      bf16x8 tf = *(const bf16x8*)(&Tb[l15][kk*32 + q*8]);
      bf16x8 wv = *(const bf16x8*)(denf + ((kk*8+t)*64 + lane)*8);
      acc = mfma16(wv, tf, acc);
    }
    size_t idx = (size_t)(row0+l15)*128 + t*16 + q*4;
    f32x4 bv = ldin4(denb, (size_t)iidx*128 + t*16 + q*4, isbf);
    f32x4 xv = *(const f32x4*)(X + idx);
    f32x4 xn;
    #pragma unroll
    for(int r=0;r<4;r++) xn[r] = xv[r] + acc[r] + bv[r];
    if(l15 < 8){
      *(f32x4*)(X + idx) = xn;
      if(last){
        if(isbf){
          u32x2 o; o[0]=pk2(xn[0],xn[1]); o[1]=pk2(xn[2],xn[3]);
          *(u32x2*)((u16*)OUT + idx) = o;
        } else {
          *(f32x4*)((float*)OUT + idx) = xn;
        }
      }
    }
    if(!last){
      u32x2 d; d[0]=pk2(xn[0],xn[1]); d[1]=pk2(xn[2],xn[3]);
      *(u32x2*)(&Xw[l15][t*16 + q*4]) = d;
    }
  }
  if(!last){
    __syncthreads();
    // ---- Phase 3: y_next = x_new @ in2f_next (other Y buffer); l15<8 stores.
    {
      int t = widx;
      f32x4 acc = (f32x4){0.f,0.f,0.f,0.f};
      #pragma unroll
      for(int kk=0;kk<4;kk++){
        bf16x8 xf = *(const bf16x8*)(&Xw[l15][kk*32 + q*8]);
        bf16x8 wv = *(const bf16x8*)(in2fN + ((kk*8+t)*64 + lane)*8);
        acc = mfma16(wv, xf, acc);
      }
      if(l15 < 8)
        *(f32x4*)(Yw + (size_t)(row0+l15)*128 + t*16 + q*4) = acc;
    }
  }
}

// ---------------------------------------------------------------------------
extern "C" void kernel_launch(void* const* d_in, const int* in_sizes, int n_in,
                              void* d_out, int out_size, void* d_ws, size_t ws_size,
                              hipStream_t stream){
  const void* pos   = d_in[0];
  const void* cell  = d_in[1];
  const void* cello = d_in[2];
  const void* nmask = d_in[3];
  // d_in[4] atom_mask: unused by the output
  const void* emb   = d_in[5];
  const void* fw1   = d_in[6];
  const void* fb1   = d_in[7];
  const void* fw2   = d_in[8];
  const void* fb2   = d_in[9];
  const void* in2f  = d_in[10];
  const void* f2o   = d_in[11];
  const void* f2ob  = d_in[12];
  const void* den   = d_in[13];
  const void* denb  = d_in[14];
  const int* z      = (const int*)d_in[15];
  const int* nbrs   = (const int*)d_in[16];

  char* ws = (char*)d_ws;
  float* X    = (float*)(ws);                 //  4 MB fp32 features
  float* Y    = (float*)(ws +  4194304);      //  4 MB projected features (ping)
  float* Y2   = (float*)(ws +  8388608);      //  4 MB projected features (pong)
  u32x2* DESC = (u32x2*)(ws + 12582912);      //  4 MB pair descriptors
  u16*   WF   = (u16*)  (ws + 16777216);      // 432 KB weight B-frags
  u32x2* TT   = (u32x2*)(ws + 17301504);      //  3 MB interleaved knot-pair table
  u32*   CNT  = (u32*)  (ws + 20447232);      // 32 KB per-atom active counts

  k_setup<<<3368, 256, 0, stream>>>(pos, cell, cello, nmask, emb,
                                    fw1, fb1, fw2, fb2, in2f, f2o, den,
                                    z, nbrs, X, DESC, CNT, WF, TT, Y);

  for(int i=0;i<3;i++){
    const u16* base = WF + (size_t)i*WF_STRIDE;
    const u16* in2fN = (i<2) ? (WF + (size_t)(i+1)*WF_STRIDE + WF_IN2F) : WF;
    const float* Yrd = (i&1) ? Y2 : Y;
    float*       Ywr = (i&1) ? Y  : Y2;
    k_iter<<<1024, 512, 0, stream>>>(DESC, CNT, TT + (size_t)i*NKNOT*64, Yrd, X, Ywr,
                                     base + WF_F2O, base + WF_DEN, in2fN,
                                     f2ob, denb, nmask,
                                     d_out, (i==2) ? 1 : 0, i);
  }
}